// Round 5
// baseline (258.625 us; speedup 1.0000x reference)
//
#include <hip/hip_runtime.h>

typedef unsigned int u32;
typedef float f32x4 __attribute__((ext_vector_type(4)));

#define BB 8
#define SS 2048
#define KK 16
#define RR 16
#define DIN 2048
#define DOUT 2048

// ---------------------------------------------------------------------------
// Kernel 1: mix the banks (all fp32).
//   Am[b][r][i] = sum_k alpha[b][k] * A_bank[k][r][i]
//   Bm[b][o][r] = sum_k alpha[b][k] * B_bank[k][o][r]
// ---------------------------------------------------------------------------
__global__ void __launch_bounds__(256) mix_kernel(
    const float* __restrict__ alpha,
    const float* __restrict__ A_bank,
    const float* __restrict__ B_bank,
    float* __restrict__ Am,
    float* __restrict__ Bm)
{
    int t = blockIdx.x * 256 + threadIdx.x;
    const int half = BB * RR * DIN;  // 262144
    if (t < half) {
        // t = (b*RR + r)*DIN + i   (i fastest -> coalesced)
        int i = t & (DIN - 1);
        int r = (t >> 11) & (RR - 1);
        int b = t >> 15;
        float acc = 0.f;
#pragma unroll
        for (int k = 0; k < KK; ++k)
            acc += alpha[b * KK + k] * A_bank[(k * RR + r) * DIN + i];
        Am[t] = acc;
    } else {
        int u = t - half;
        // u = (b*DOUT + o)*RR + r  (r fastest -> coalesced)
        int r = u & (RR - 1);
        int o = (u >> 4) & (DOUT - 1);
        int b = u >> 15;
        float acc = 0.f;
#pragma unroll
        for (int k = 0; k < KK; ++k)
            acc += alpha[b * KK + k] * B_bank[(k * DOUT + o) * RR + r];
        Bm[u] = acc;
    }
}

// ---------------------------------------------------------------------------
// Kernel 2 (fused): per block, one 16-row s-tile of batch b.
//   Phase 1: z[s][r] = sum_i Am[b][r][i] * h[b][s][i]  -> LDS (1 KB)
//     wave owns 4 s rows; lanes span i; acc[4][16] in regs; i-chunk loop
//     unroll 1 (unroll-8 spilled in round 1: VGPR=256, 183 MB scratch).
//     Tree reduction with payload halving (63 shfl); lane l ends with
//     value j*16+r -> zl[(wid*4 + l/16)*16 + l%16].
//   Phase 2: delta[s][o] = sum_r Bm[b][o][r] * z_lds[s][r]
//     z from LDS same-address broadcast (no global latency chain — round-4
//     delta was suspected latency-bound on its global z loads at 2 blk/CU).
//     2 o-tiles x 16 s, nontemporal f32x4 stores.
// Grid: (S/16, B) = (128, 8), 256 threads.
// ---------------------------------------------------------------------------
__global__ void __launch_bounds__(256, 4) zdelta_kernel(
    const float* __restrict__ h,
    const float* __restrict__ Am,
    const float* __restrict__ Bm,
    float* __restrict__ out)
{
    __shared__ float zl[16 * 16];

    int b = blockIdx.y;
    int wid = threadIdx.x >> 6;
    int lane = threadIdx.x & 63;
    int stile = blockIdx.x * 16;
    int s0 = stile + wid * 4;

    const float* hb = h + ((size_t)b * SS + s0) * DIN;
    const float* Ab = Am + (size_t)b * RR * DIN;

    // ---- Phase 1: z for 4 s rows per wave ----
    float a[64];
#pragma unroll
    for (int v = 0; v < 64; ++v) a[v] = 0.f;

#pragma unroll 1
    for (int t = 0; t < 8; ++t) {
        int i0 = t * 256 + lane * 4;
        f32x4 hv0 = __builtin_nontemporal_load((const f32x4*)(hb + i0));
        f32x4 hv1 = __builtin_nontemporal_load((const f32x4*)(hb + DIN + i0));
        f32x4 hv2 = __builtin_nontemporal_load((const f32x4*)(hb + 2 * DIN + i0));
        f32x4 hv3 = __builtin_nontemporal_load((const f32x4*)(hb + 3 * DIN + i0));
#pragma unroll
        for (int r = 0; r < 16; ++r) {
            f32x4 av = *(const f32x4*)(Ab + r * DIN + i0);
            a[0 * 16 + r] += hv0.x * av.x + hv0.y * av.y + hv0.z * av.z + hv0.w * av.w;
            a[1 * 16 + r] += hv1.x * av.x + hv1.y * av.y + hv1.z * av.z + hv1.w * av.w;
            a[2 * 16 + r] += hv2.x * av.x + hv2.y * av.y + hv2.z * av.z + hv2.w * av.w;
            a[3 * 16 + r] += hv3.x * av.x + hv3.y * av.y + hv3.z * av.z + hv3.w * av.w;
        }
    }

    // Cross-lane tree reduction, payload halving each step (63 shfl total).
#pragma unroll
    for (int off = 32; off >= 1; off >>= 1) {
        bool up = (lane & off) != 0;
#pragma unroll
        for (int v = 0; v < off; ++v) {
            float send = up ? a[v] : a[v + off];
            float keep = up ? a[v + off] : a[v];
            a[v] = keep + __shfl_xor(send, off, 64);
        }
    }
    // lane l holds z[s0 + l/16][l%16]
    zl[(wid * 4 + (lane >> 4)) * 16 + (lane & 15)] = a[0];
    __syncthreads();

    // ---- Phase 2: delta for the 16-row s-tile ----
    int tx = threadIdx.x;
#pragma unroll 1
    for (int ot = 0; ot < 2; ++ot) {
        int o0 = ot * 1024 + tx * 4;
        const float* wp = Bm + ((size_t)b * DOUT + o0) * RR;  // 64 contiguous
        float w[4][16];
#pragma unroll
        for (int j = 0; j < 4; ++j) {
#pragma unroll
            for (int q = 0; q < 4; ++q) {
                f32x4 p = *(const f32x4*)(wp + j * 16 + q * 4);
                w[j][q * 4 + 0] = p.x; w[j][q * 4 + 1] = p.y;
                w[j][q * 4 + 2] = p.z; w[j][q * 4 + 3] = p.w;
            }
        }

        float* op = out + ((size_t)b * SS + stile) * DOUT + o0;
#pragma unroll 2
        for (int s = 0; s < 16; ++s) {
            // same-address LDS reads -> broadcast, conflict-free
            f32x4 z0 = *(const f32x4*)(&zl[s * 16 + 0]);
            f32x4 z1 = *(const f32x4*)(&zl[s * 16 + 4]);
            f32x4 z2 = *(const f32x4*)(&zl[s * 16 + 8]);
            f32x4 z3 = *(const f32x4*)(&zl[s * 16 + 12]);
            float zz[16] = {z0.x, z0.y, z0.z, z0.w, z1.x, z1.y, z1.z, z1.w,
                            z2.x, z2.y, z2.z, z2.w, z3.x, z3.y, z3.z, z3.w};
            float rj[4];
#pragma unroll
            for (int j = 0; j < 4; ++j) {
                float acc = 0.f;
#pragma unroll
                for (int r = 0; r < 16; ++r) acc += w[j][r] * zz[r];
                rj[j] = acc;
            }
            f32x4 res;
            res.x = rj[0]; res.y = rj[1]; res.z = rj[2]; res.w = rj[3];
            __builtin_nontemporal_store(res, (f32x4*)(op + (size_t)s * DOUT));
        }
    }
}

// ---------------------------------------------------------------------------
extern "C" void kernel_launch(void* const* d_in, const int* in_sizes, int n_in,
                              void* d_out, int out_size, void* d_ws, size_t ws_size,
                              hipStream_t stream)
{
    const float* h      = (const float*)d_in[0];   // [B][S][DIN]   fp32
    const float* alpha  = (const float*)d_in[1];   // [B][K]        fp32
    const float* A_bank = (const float*)d_in[2];   // [K][R][DIN]   fp32
    const float* B_bank = (const float*)d_in[3];   // [K][DOUT][R]  fp32
    float* out = (float*)d_out;                    // [B][S][DOUT]  fp32

    // workspace layout (4 MiB total):
    float* Am = (float*)d_ws;                      // [B][R][DIN]  fp32, 2 MiB
    float* Bm = Am + BB * RR * DIN;                // [B][DOUT][R] fp32, 2 MiB

    mix_kernel<<<2048, 256, 0, stream>>>(alpha, A_bank, B_bank, Am, Bm);
    zdelta_kernel<<<dim3(128, 8), 256, 0, stream>>>(h, Am, Bm, out);
}